// Round 1
// baseline (145.861 us; speedup 1.0000x reference)
//
#include <hip/hip_runtime.h>

typedef __bf16 bf16x8 __attribute__((ext_vector_type(8)));
typedef float  f32x4  __attribute__((ext_vector_type(4)));
typedef unsigned short u16x8 __attribute__((ext_vector_type(8)));

// ws layout (ushort elements):
//   [0      .. 4095 ]  Wt0 : [128 n][32 k] bf16, k>=4 zero-padded  (8 KB)
//   [4096   .. 86015]  Wth : [5][128 n][128 k] bf16 (transposed)   (160 KB)
//   [86016  .. 86271]  WLt : [2 c][128 k] bf16                     (512 B)
#define WS_WT0 0
#define WS_WTH 4096
#define WS_WLT 86016

__device__ __forceinline__ unsigned short f2b(float f) {
  return __builtin_bit_cast(unsigned short, (__bf16)f);
}
__device__ __forceinline__ float b2f(unsigned short u) {
  unsigned int i = ((unsigned int)u) << 16;
  return __builtin_bit_cast(float, i);
}

__global__ void prep_kernel(const float* __restrict__ W0,
                            const float* __restrict__ Wh,
                            const float* __restrict__ WL,
                            unsigned short* __restrict__ ws) {
  int i = blockIdx.x * 256 + threadIdx.x;
  if (i < 4096) {                       // Wt0[n][k] = k<4 ? W0[k][n] : 0
    int n = i >> 5, k = i & 31;
    float v = (k < 4) ? W0[k * 128 + n] : 0.f;
    ws[WS_WT0 + i] = f2b(v);
  } else if (i < 86016) {               // Wth[l][n][k] = Wh[l][k][n]
    int j = i - 4096;
    int l = j >> 14, r = j & 16383;
    int n = r >> 7, k = r & 127;
    ws[i] = f2b(Wh[(l * 128 + k) * 128 + n]);
  } else if (i < 86272) {               // WLt[c][k] = WL[k][c]
    int j = i - 86016;
    int c = j >> 7, k = j & 127;
    ws[i] = f2b(WL[k * 2 + c]);
  }
}

// swizzled LDS byte address for H tiles: row stride 256B, XOR bank swizzle
__device__ __forceinline__ int swz(int row, int byteoff) {
  return row * 256 + (byteoff ^ ((row & 7) << 4));
}

__launch_bounds__(256, 2)
__global__ void mlp_kernel(const float* __restrict__ X,
                           const float* __restrict__ nu_min_p,
                           const float* __restrict__ nu_max_p,
                           const float* __restrict__ b0,
                           const float* __restrict__ bh,
                           const float* __restrict__ bL,
                           const unsigned short* __restrict__ ws,
                           float* __restrict__ out) {
  __shared__ __align__(16) char Hb[2][128 * 256];  // two [128][128] bf16 buffers
  const int tid  = threadIdx.x;
  const int lane = tid & 63;
  const int wid  = tid >> 6;
  const int row0 = blockIdx.x * 128;
  const int lm = lane & 15;
  const int lh = lane >> 4;

  // ---- stage scaled inputs (K padded to 32) into Hb[0] ----
  if (tid < 128) {
    const float4 xv = reinterpret_cast<const float4*>(X)[row0 + tid];
    const float numin = nu_min_p[0], numax = nu_max_p[0];
    const float v0 = xv.x;                              // x in [-1,1] -> x
    const float v1 = xv.y;
    const float v2 = 2.f * xv.z - 1.f;                  // t in [0,1]
    const float v3 = 2.f * (xv.w - numin) / (numax - numin) - 1.f;
    uint4 c0;
    c0.x = (unsigned)f2b(v0) | ((unsigned)f2b(v1) << 16);
    c0.y = (unsigned)f2b(v2) | ((unsigned)f2b(v3) << 16);
    c0.z = 0u; c0.w = 0u;
    const uint4 z4 = make_uint4(0u, 0u, 0u, 0u);
    *reinterpret_cast<uint4*>(Hb[0] + swz(tid, 0))  = c0;
    *reinterpret_cast<uint4*>(Hb[0] + swz(tid, 16)) = z4;
    *reinterpret_cast<uint4*>(Hb[0] + swz(tid, 32)) = z4;
    *reinterpret_cast<uint4*>(Hb[0] + swz(tid, 48)) = z4;
  }

  const int nbase = (wid & 1) * 64;   // output-channel strip
  const int pbase = (wid >> 1) * 64;  // point strip
  const f32x4 zero4 = {0.f, 0.f, 0.f, 0.f};

  // ================= Layer 0 : K = 32 =================
  {
    bf16x8 aw[4];
#pragma unroll
    for (int nt = 0; nt < 4; ++nt) {
      const int n = nbase + nt * 16 + lm;
      aw[nt] = __builtin_bit_cast(bf16x8, *reinterpret_cast<const uint4*>(
                 reinterpret_cast<const char*>(ws + WS_WT0) + n * 64 + lh * 16));
    }
    f32x4 bv[4];
#pragma unroll
    for (int nt = 0; nt < 4; ++nt)
      bv[nt] = *reinterpret_cast<const f32x4*>(b0 + nbase + nt * 16 + lh * 4);

    f32x4 acc[4][4];
#pragma unroll
    for (int nt = 0; nt < 4; ++nt)
#pragma unroll
      for (int pt = 0; pt < 4; ++pt) acc[nt][pt] = zero4;

    __syncthreads();
#pragma unroll
    for (int pt = 0; pt < 4; ++pt) {
      const int p = pbase + pt * 16 + lm;
      const bf16x8 bfr = __builtin_bit_cast(bf16x8,
          *reinterpret_cast<const uint4*>(Hb[0] + swz(p, lh * 16)));
#pragma unroll
      for (int nt = 0; nt < 4; ++nt)
        acc[nt][pt] = __builtin_amdgcn_mfma_f32_16x16x32_bf16(aw[nt], bfr, acc[nt][pt], 0, 0, 0);
    }
    // epilogue: bias + swish -> bf16 -> Hb[1]
#pragma unroll
    for (int nt = 0; nt < 4; ++nt) {
#pragma unroll
      for (int pt = 0; pt < 4; ++pt) {
        const int p  = pbase + pt * 16 + lm;
        const int n0 = nbase + nt * 16 + lh * 4;
        unsigned short q[4];
#pragma unroll
        for (int r = 0; r < 4; ++r) {
          const float z = acc[nt][pt][r] + bv[nt][r];
          const float s = z / (1.f + __expf(-z));
          q[r] = f2b(s);
        }
        uint2 wv;
        wv.x = (unsigned)q[0] | ((unsigned)q[1] << 16);
        wv.y = (unsigned)q[2] | ((unsigned)q[3] << 16);
        *reinterpret_cast<uint2*>(Hb[1] + swz(p, n0 * 2)) = wv;
      }
    }
  }

  // ================= 5 hidden layers : K = 128 =================
#pragma unroll 1
  for (int h = 0; h < 5; ++h) {
    const char* wbase = reinterpret_cast<const char*>(ws + WS_WTH) + h * 32768;
    const float* bias = bh + h * 128;
    char* Hin  = Hb[1 - (h & 1)];
    char* Hout = Hb[h & 1];

    bf16x8 aw[4][4];
#pragma unroll
    for (int nt = 0; nt < 4; ++nt) {
      const int n = nbase + nt * 16 + lm;
#pragma unroll
      for (int ks = 0; ks < 4; ++ks)
        aw[nt][ks] = __builtin_bit_cast(bf16x8, *reinterpret_cast<const uint4*>(
                       wbase + n * 256 + ks * 64 + lh * 16));
    }
    f32x4 bv[4];
#pragma unroll
    for (int nt = 0; nt < 4; ++nt)
      bv[nt] = *reinterpret_cast<const f32x4*>(bias + nbase + nt * 16 + lh * 4);

    f32x4 acc[4][4];
#pragma unroll
    for (int nt = 0; nt < 4; ++nt)
#pragma unroll
      for (int pt = 0; pt < 4; ++pt) acc[nt][pt] = zero4;

    __syncthreads();
#pragma unroll
    for (int pt = 0; pt < 4; ++pt) {
      const int p = pbase + pt * 16 + lm;
#pragma unroll
      for (int ks = 0; ks < 4; ++ks) {
        const bf16x8 bfr = __builtin_bit_cast(bf16x8,
            *reinterpret_cast<const uint4*>(Hin + swz(p, ks * 64 + lh * 16)));
#pragma unroll
        for (int nt = 0; nt < 4; ++nt)
          acc[nt][pt] = __builtin_amdgcn_mfma_f32_16x16x32_bf16(aw[nt][ks], bfr, acc[nt][pt], 0, 0, 0);
      }
    }
#pragma unroll
    for (int nt = 0; nt < 4; ++nt) {
#pragma unroll
      for (int pt = 0; pt < 4; ++pt) {
        const int p  = pbase + pt * 16 + lm;
        const int n0 = nbase + nt * 16 + lh * 4;
        unsigned short q[4];
#pragma unroll
        for (int r = 0; r < 4; ++r) {
          const float z = acc[nt][pt][r] + bv[nt][r];
          const float s = z / (1.f + __expf(-z));
          q[r] = f2b(s);
        }
        uint2 wv;
        wv.x = (unsigned)q[0] | ((unsigned)q[1] << 16);
        wv.y = (unsigned)q[2] | ((unsigned)q[3] << 16);
        *reinterpret_cast<uint2*>(Hout + swz(p, n0 * 2)) = wv;
      }
    }
  }

  // ================= final layer : [128 -> 2], fp32 =================
  __syncthreads();
  {
    const char* Hfin = Hb[0];   // after L0 + 5 hidden layers, result is in buffer 0
    const int p = tid >> 1, c = tid & 1;
    const unsigned short* wl = ws + WS_WLT + c * 128;
    float acc = bL[c];
#pragma unroll
    for (int kk = 0; kk < 16; ++kk) {
      const u16x8 hv = __builtin_bit_cast(u16x8,
          *reinterpret_cast<const uint4*>(Hfin + swz(p, kk * 16)));
      const u16x8 wv = __builtin_bit_cast(u16x8,
          *reinterpret_cast<const uint4*>(wl + kk * 8));
#pragma unroll
      for (int j = 0; j < 8; ++j) acc += b2f(hv[j]) * b2f(wv[j]);
    }
    out[(row0 + p) * 2 + c] = acc;
  }
}

extern "C" void kernel_launch(void* const* d_in, const int* in_sizes, int n_in,
                              void* d_out, int out_size, void* d_ws, size_t ws_size,
                              hipStream_t stream) {
  const float* X     = (const float*)d_in[0];
  const float* numin = (const float*)d_in[1];
  const float* numax = (const float*)d_in[2];
  const float* W0    = (const float*)d_in[3];
  const float* b0    = (const float*)d_in[4];
  const float* Wh    = (const float*)d_in[5];
  const float* bh    = (const float*)d_in[6];
  const float* WL    = (const float*)d_in[7];
  const float* bL    = (const float*)d_in[8];
  unsigned short* ws = (unsigned short*)d_ws;
  float* out = (float*)d_out;

  hipLaunchKernelGGL(prep_kernel, dim3(338), dim3(256), 0, stream, W0, Wh, WL, ws);
  hipLaunchKernelGGL(mlp_kernel, dim3(2048), dim3(256), 0, stream,
                     X, numin, numax, b0, bh, bL, ws, out);
}

// Round 2
// 96.159 us; speedup vs baseline: 1.5169x; 1.5169x over previous
//
#include <hip/hip_runtime.h>

typedef __bf16 bf16x8 __attribute__((ext_vector_type(8)));
typedef float  f32x4  __attribute__((ext_vector_type(4)));

// ws layout (ushort elements):
//   [0      .. 4095 ]  Wt0 : [128 n][32 k] bf16, k>=4 zero-padded  (8 KB)
//   [4096   .. 86015]  Wth : [5][128 n][128 k] bf16 (transposed)   (160 KB)
//   [86016  .. 88063]  WLp : [16 n][128 k] bf16, n>=2 zero-padded  (4 KB)
#define WS_WT0 0
#define WS_WTH 4096
#define WS_WLT 86016

__device__ __forceinline__ unsigned short f2b(float f) {
  return __builtin_bit_cast(unsigned short, (__bf16)f);
}

__device__ __forceinline__ float swish(float z) {
  // z * sigmoid(z) via v_exp + v_rcp (no IEEE div sequence)
  return z * __builtin_amdgcn_rcpf(1.f + __expf(-z));
}

__global__ void prep_kernel(const float* __restrict__ W0,
                            const float* __restrict__ Wh,
                            const float* __restrict__ WL,
                            unsigned short* __restrict__ ws) {
  int i = blockIdx.x * 256 + threadIdx.x;
  if (i < 4096) {                       // Wt0[n][k] = k<4 ? W0[k][n] : 0
    int n = i >> 5, k = i & 31;
    float v = (k < 4) ? W0[k * 128 + n] : 0.f;
    ws[WS_WT0 + i] = f2b(v);
  } else if (i < 86016) {               // Wth[l][n][k] = Wh[l][k][n]
    int j = i - 4096;
    int l = j >> 14, r = j & 16383;
    int n = r >> 7, k = r & 127;
    ws[i] = f2b(Wh[(l * 128 + k) * 128 + n]);
  } else if (i < 88064) {               // WLp[n][k] = n<2 ? WL[k][n] : 0
    int j = i - 86016;
    int n = j >> 7, k = j & 127;
    float v = (n < 2) ? WL[k * 2 + n] : 0.f;
    ws[i] = f2b(v);
  }
}

__launch_bounds__(256, 4)
__global__ void mlp_kernel(const float* __restrict__ X,
                           const float* __restrict__ nu_min_p,
                           const float* __restrict__ nu_max_p,
                           const float* __restrict__ b0,
                           const float* __restrict__ bh,
                           const float* __restrict__ bL,
                           const unsigned short* __restrict__ ws,
                           float* __restrict__ out) {
  __shared__ __align__(16) char Hs[128 * 256];  // single [128 pt][128 ch] bf16 tile
  const int tid  = threadIdx.x;
  const int lane = tid & 63;
  const int wid  = tid >> 6;
  const int row0 = blockIdx.x * 128;
  const int lm = lane & 15;
  const int lh = lane >> 4;
  const int xorv = (lm & 7) << 4;       // row-swizzle XOR (p&7 == lm&7 everywhere)

  // ---- stage scaled inputs (K padded to 32) ----
  if (tid < 128) {
    const float4 xv = reinterpret_cast<const float4*>(X)[row0 + tid];
    const float numin = nu_min_p[0], numax = nu_max_p[0];
    const float v0 = xv.x;
    const float v1 = xv.y;
    const float v2 = 2.f * xv.z - 1.f;
    const float v3 = 2.f * (xv.w - numin) / (numax - numin) - 1.f;
    uint4 c0;
    c0.x = (unsigned)f2b(v0) | ((unsigned)f2b(v1) << 16);
    c0.y = (unsigned)f2b(v2) | ((unsigned)f2b(v3) << 16);
    c0.z = 0u; c0.w = 0u;
    const uint4 z4 = make_uint4(0u, 0u, 0u, 0u);
    const int xr = (tid & 7) << 4;
    *reinterpret_cast<uint4*>(Hs + tid * 256 + (0  ^ xr)) = c0;
    *reinterpret_cast<uint4*>(Hs + tid * 256 + (16 ^ xr)) = z4;
    *reinterpret_cast<uint4*>(Hs + tid * 256 + (32 ^ xr)) = z4;
    *reinterpret_cast<uint4*>(Hs + tid * 256 + (48 ^ xr)) = z4;
  }

  const int nbase = (wid & 1) * 64;   // output-channel strip
  const int pbase = (wid >> 1) * 64;  // point strip

  f32x4 acc[4][4];

  // ================= Layer 0 : K = 32 =================
  {
#pragma unroll
    for (int nt = 0; nt < 4; ++nt) {
      const f32x4 bv = *reinterpret_cast<const f32x4*>(b0 + nbase + nt * 16 + lh * 4);
#pragma unroll
      for (int pt = 0; pt < 4; ++pt) acc[nt][pt] = bv;
    }
    __syncthreads();
    bf16x8 bfr[4];
#pragma unroll
    for (int pt = 0; pt < 4; ++pt) {
      const int p = pbase + pt * 16 + lm;
      bfr[pt] = __builtin_bit_cast(bf16x8,
          *reinterpret_cast<const uint4*>(Hs + p * 256 + ((lh * 16) ^ xorv)));
    }
#pragma unroll
    for (int nt = 0; nt < 4; ++nt) {
      const int n = nbase + nt * 16 + lm;
      const bf16x8 a = __builtin_bit_cast(bf16x8, *reinterpret_cast<const uint4*>(
          reinterpret_cast<const char*>(ws + WS_WT0) + n * 64 + lh * 16));
#pragma unroll
      for (int pt = 0; pt < 4; ++pt)
        acc[nt][pt] = __builtin_amdgcn_mfma_f32_16x16x32_bf16(a, bfr[pt], acc[nt][pt], 0, 0, 0);
    }
    __syncthreads();
#pragma unroll
    for (int nt = 0; nt < 4; ++nt) {
#pragma unroll
      for (int pt = 0; pt < 4; ++pt) {
        const int p  = pbase + pt * 16 + lm;
        const int n0 = nbase + nt * 16 + lh * 4;
        unsigned short q[4];
#pragma unroll
        for (int r = 0; r < 4; ++r) q[r] = f2b(swish(acc[nt][pt][r]));
        uint2 wv;
        wv.x = (unsigned)q[0] | ((unsigned)q[1] << 16);
        wv.y = (unsigned)q[2] | ((unsigned)q[3] << 16);
        *reinterpret_cast<uint2*>(Hs + p * 256 + ((n0 * 2) ^ xorv)) = wv;
      }
    }
  }

  // ================= 5 hidden layers : K = 128, in-place =================
#pragma unroll 1
  for (int h = 0; h < 5; ++h) {
    const char* wbase = reinterpret_cast<const char*>(ws + WS_WTH) + h * 32768;
    const float* bias = bh + h * 128;

#pragma unroll
    for (int nt = 0; nt < 4; ++nt) {
      const f32x4 bv = *reinterpret_cast<const f32x4*>(bias + nbase + nt * 16 + lh * 4);
#pragma unroll
      for (int pt = 0; pt < 4; ++pt) acc[nt][pt] = bv;
    }
    __syncthreads();   // previous layer's writes visible
#pragma unroll 1
    for (int ks = 0; ks < 4; ++ks) {
      bf16x8 bfr[4];
#pragma unroll
      for (int pt = 0; pt < 4; ++pt) {
        const int p = pbase + pt * 16 + lm;
        bfr[pt] = __builtin_bit_cast(bf16x8,
            *reinterpret_cast<const uint4*>(Hs + p * 256 + ((ks * 64 + lh * 16) ^ xorv)));
      }
#pragma unroll
      for (int nt = 0; nt < 4; ++nt) {
        const int n = nbase + nt * 16 + lm;
        const bf16x8 a = __builtin_bit_cast(bf16x8,
            *reinterpret_cast<const uint4*>(wbase + n * 256 + ks * 64 + lh * 16));
#pragma unroll
        for (int pt = 0; pt < 4; ++pt)
          acc[nt][pt] = __builtin_amdgcn_mfma_f32_16x16x32_bf16(a, bfr[pt], acc[nt][pt], 0, 0, 0);
      }
    }
    __syncthreads();   // all reads of Hs complete before overwrite
#pragma unroll
    for (int nt = 0; nt < 4; ++nt) {
#pragma unroll
      for (int pt = 0; pt < 4; ++pt) {
        const int p  = pbase + pt * 16 + lm;
        const int n0 = nbase + nt * 16 + lh * 4;
        unsigned short q[4];
#pragma unroll
        for (int r = 0; r < 4; ++r) q[r] = f2b(swish(acc[nt][pt][r]));
        uint2 wv;
        wv.x = (unsigned)q[0] | ((unsigned)q[1] << 16);
        wv.y = (unsigned)q[2] | ((unsigned)q[3] << 16);
        *reinterpret_cast<uint2*>(Hs + p * 256 + ((n0 * 2) ^ xorv)) = wv;
      }
    }
  }

  // ================= final layer : [128 -> 2] via MFMA =================
  __syncthreads();
  {
    const char* wl = reinterpret_cast<const char*>(ws + WS_WLT);
    const float bl0 = bL[0], bl1 = bL[1];
    f32x4 accL[2];
#pragma unroll
    for (int pt2 = 0; pt2 < 2; ++pt2) {
      accL[pt2] = f32x4{0.f, 0.f, 0.f, 0.f};
      const int p = wid * 32 + pt2 * 16 + lm;
#pragma unroll
      for (int ks = 0; ks < 4; ++ks) {
        const bf16x8 bfr = __builtin_bit_cast(bf16x8,
            *reinterpret_cast<const uint4*>(Hs + p * 256 + ((ks * 64 + lh * 16) ^ xorv)));
        const bf16x8 a = __builtin_bit_cast(bf16x8,
            *reinterpret_cast<const uint4*>(wl + lm * 256 + ks * 64 + lh * 16));
        accL[pt2] = __builtin_amdgcn_mfma_f32_16x16x32_bf16(a, bfr, accL[pt2], 0, 0, 0);
      }
    }
    if (lh == 0) {
#pragma unroll
      for (int pt2 = 0; pt2 < 2; ++pt2) {
        const int p = wid * 32 + pt2 * 16 + lm;
        float2 o;
        o.x = accL[pt2][0] + bl0;
        o.y = accL[pt2][1] + bl1;
        *reinterpret_cast<float2*>(out + (size_t)(row0 + p) * 2) = o;
      }
    }
  }
}

extern "C" void kernel_launch(void* const* d_in, const int* in_sizes, int n_in,
                              void* d_out, int out_size, void* d_ws, size_t ws_size,
                              hipStream_t stream) {
  const float* X     = (const float*)d_in[0];
  const float* numin = (const float*)d_in[1];
  const float* numax = (const float*)d_in[2];
  const float* W0    = (const float*)d_in[3];
  const float* b0    = (const float*)d_in[4];
  const float* Wh    = (const float*)d_in[5];
  const float* bh    = (const float*)d_in[6];
  const float* WL    = (const float*)d_in[7];
  const float* bL    = (const float*)d_in[8];
  unsigned short* ws = (unsigned short*)d_ws;
  float* out = (float*)d_out;

  hipLaunchKernelGGL(prep_kernel, dim3(344), dim3(256), 0, stream, W0, Wh, WL, ws);
  hipLaunchKernelGGL(mlp_kernel, dim3(2048), dim3(256), 0, stream,
                     X, numin, numax, b0, bh, bL, ws, out);
}

// Round 3
// 81.648 us; speedup vs baseline: 1.7865x; 1.1777x over previous
//
#include <hip/hip_runtime.h>

typedef __bf16 bf16x8 __attribute__((ext_vector_type(8)));
typedef float  f32x4  __attribute__((ext_vector_type(4)));

// ws layout (bytes). All A-operand fragments stored lane-linear:
// one frag = 1024 B; lane l's 16 B at frag_base + l*16 (fully coalesced load).
//   WT0 : 8 frags   (nt 0..7)            bytes [0      .. 8191  ]
//   WTH : 160 frags ((h*4+ks)*8 + nt)    bytes [8192   .. 172031]
//   WLT : 4 frags   (ks 0..3)            bytes [172032 .. 176127]
#define WS_WT0_B 0
#define WS_WTH_B 8192
#define WS_WLT_B 172032

__device__ __forceinline__ unsigned short f2b(float f) {
  return __builtin_bit_cast(unsigned short, (__bf16)f);
}

__global__ void prep_kernel(const float* __restrict__ W0,
                            const float* __restrict__ Wh,
                            const float* __restrict__ WL,
                            unsigned short* __restrict__ ws) {
  int i = blockIdx.x * 256 + threadIdx.x;   // ushort index == (byte/2)
  int l  = (i >> 3) & 63;                   // lane within frag
  int j  = i & 7;                           // element within lane's 8
  int lm = l & 15, lh = l >> 4;
  if (i < 4096) {                           // WT0, frag nt = i>>9 ; K=32 zero-padded
    int nt = i >> 9;
    int n = nt * 16 + lm, k = lh * 8 + j;
    ws[i] = f2b(k < 4 ? W0[k * 128 + n] : 0.f);
  } else if (i < 86016) {                   // WTH
    int t = i - 4096;
    int frag = t >> 9;                      // (h*4+ks)*8 + nt
    int nt = frag & 7, ks = (frag >> 3) & 3, h = frag >> 5;
    int n = nt * 16 + lm, k = ks * 32 + lh * 8 + j;
    ws[i] = f2b(Wh[(h * 128 + k) * 128 + n]);
  } else if (i < 88064) {                   // WLT, frag ks ; n>=2 zero-padded
    int t = i - 86016;
    int ks = t >> 9;
    int n = lm, k = ks * 32 + lh * 8 + j;
    ws[i] = f2b(n < 2 ? WL[k * 2 + n] : 0.f);
  }
}

__device__ __forceinline__ f32x4 swish4(f32x4 z) {
  f32x4 e;
  e[0] = __expf(-z[0]); e[1] = __expf(-z[1]);
  e[2] = __expf(-z[2]); e[3] = __expf(-z[3]);
  const f32x4 w = e + 1.f;                  // v_pk_add_f32 x2
  f32x4 s;
  s[0] = __builtin_amdgcn_rcpf(w[0]); s[1] = __builtin_amdgcn_rcpf(w[1]);
  s[2] = __builtin_amdgcn_rcpf(w[2]); s[3] = __builtin_amdgcn_rcpf(w[3]);
  return z * s;                             // v_pk_mul_f32 x2
}

// One wave per block; each wave owns 32 points through ALL layers. No barriers.
__launch_bounds__(64, 4)
__global__ void mlp_kernel(const float* __restrict__ X,
                           const float* __restrict__ nu_min_p,
                           const float* __restrict__ nu_max_p,
                           const float* __restrict__ b0,
                           const float* __restrict__ bh,
                           const float* __restrict__ bL,
                           const unsigned short* __restrict__ ws,
                           float* __restrict__ out) {
  __shared__ __align__(16) char Hs[32 * 256];   // [32 pt][128 ch] bf16, row-swizzled
  const int lane = threadIdx.x;                 // 0..63
  const int lm = lane & 15, lh = lane >> 4;
  const int row0 = blockIdx.x * 32;
  const char* wsb = reinterpret_cast<const char*>(ws);
  const int xorm = (lm & 7) << 4;               // p&7 == lm&7 for p = pt*16+lm

  // ---- stage scaled inputs (K padded to 32 -> 64B rows) ----
  if (lane < 32) {
    const float4 xv = reinterpret_cast<const float4*>(X)[row0 + lane];
    const float numin = nu_min_p[0], numax = nu_max_p[0];
    const float v0 = xv.x;                      // x already in [-1,1]
    const float v1 = xv.y;
    const float v2 = 2.f * xv.z - 1.f;
    const float v3 = 2.f * (xv.w - numin) / (numax - numin) - 1.f;
    uint4 c0;
    c0.x = (unsigned)f2b(v0) | ((unsigned)f2b(v1) << 16);
    c0.y = (unsigned)f2b(v2) | ((unsigned)f2b(v3) << 16);
    c0.z = 0u; c0.w = 0u;
    const uint4 z4 = make_uint4(0u, 0u, 0u, 0u);
    const int xr = (lane & 7) << 4;
    char* rp = Hs + lane * 256;
    *reinterpret_cast<uint4*>(rp + (0  ^ xr)) = c0;
    *reinterpret_cast<uint4*>(rp + (16 ^ xr)) = z4;
    *reinterpret_cast<uint4*>(rp + (32 ^ xr)) = z4;
    *reinterpret_cast<uint4*>(rp + (48 ^ xr)) = z4;
  }
  // single wave: DS ops are in-order per wave; no barrier needed anywhere.

  f32x4 acc[8][2];

  // ================= Layer 0 : K = 32 =================
  {
#pragma unroll
    for (int nt = 0; nt < 8; ++nt) {
      const f32x4 bv = *reinterpret_cast<const f32x4*>(b0 + nt * 16 + lh * 4);
      acc[nt][0] = bv; acc[nt][1] = bv;
    }
    bf16x8 bfr[2];
#pragma unroll
    for (int pt = 0; pt < 2; ++pt) {
      const int p = pt * 16 + lm;
      bfr[pt] = __builtin_bit_cast(bf16x8,
          *reinterpret_cast<const uint4*>(Hs + p * 256 + ((lh * 16) ^ xorm)));
    }
#pragma unroll
    for (int nt = 0; nt < 8; ++nt) {
      const bf16x8 a = __builtin_bit_cast(bf16x8,
          *reinterpret_cast<const uint4*>(wsb + WS_WT0_B + nt * 1024 + lane * 16));
      acc[nt][0] = __builtin_amdgcn_mfma_f32_16x16x32_bf16(a, bfr[0], acc[nt][0], 0, 0, 0);
      acc[nt][1] = __builtin_amdgcn_mfma_f32_16x16x32_bf16(a, bfr[1], acc[nt][1], 0, 0, 0);
    }
#pragma unroll
    for (int nt = 0; nt < 8; ++nt) {
#pragma unroll
      for (int pt = 0; pt < 2; ++pt) {
        const f32x4 r4 = swish4(acc[nt][pt]);
        unsigned short q0 = f2b(r4[0]), q1 = f2b(r4[1]), q2 = f2b(r4[2]), q3 = f2b(r4[3]);
        uint2 wv;
        wv.x = (unsigned)q0 | ((unsigned)q1 << 16);
        wv.y = (unsigned)q2 | ((unsigned)q3 << 16);
        const int p = pt * 16 + lm;
        *reinterpret_cast<uint2*>(Hs + p * 256 + (((nt * 16 + lh * 4) * 2) ^ xorm)) = wv;
      }
    }
  }

  // ================= 5 hidden layers : K = 128, in-place =================
#pragma unroll 1
  for (int h = 0; h < 5; ++h) {
    const char* wbase = wsb + WS_WTH_B + h * 32768;
    const float* bias = bh + h * 128;
#pragma unroll
    for (int nt = 0; nt < 8; ++nt) {
      const f32x4 bv = *reinterpret_cast<const f32x4*>(bias + nt * 16 + lh * 4);
      acc[nt][0] = bv; acc[nt][1] = bv;
    }
#pragma unroll 1
    for (int ks = 0; ks < 4; ++ks) {
      bf16x8 bfr[2];
#pragma unroll
      for (int pt = 0; pt < 2; ++pt) {
        const int p = pt * 16 + lm;
        bfr[pt] = __builtin_bit_cast(bf16x8,
            *reinterpret_cast<const uint4*>(Hs + p * 256 + ((ks * 64 + lh * 16) ^ xorm)));
      }
#pragma unroll
      for (int nt = 0; nt < 8; ++nt) {
        const bf16x8 a = __builtin_bit_cast(bf16x8,
            *reinterpret_cast<const uint4*>(wbase + (ks * 8 + nt) * 1024 + lane * 16));
        acc[nt][0] = __builtin_amdgcn_mfma_f32_16x16x32_bf16(a, bfr[0], acc[nt][0], 0, 0, 0);
        acc[nt][1] = __builtin_amdgcn_mfma_f32_16x16x32_bf16(a, bfr[1], acc[nt][1], 0, 0, 0);
      }
    }
#pragma unroll
    for (int nt = 0; nt < 8; ++nt) {
#pragma unroll
      for (int pt = 0; pt < 2; ++pt) {
        const f32x4 r4 = swish4(acc[nt][pt]);
        unsigned short q0 = f2b(r4[0]), q1 = f2b(r4[1]), q2 = f2b(r4[2]), q3 = f2b(r4[3]);
        uint2 wv;
        wv.x = (unsigned)q0 | ((unsigned)q1 << 16);
        wv.y = (unsigned)q2 | ((unsigned)q3 << 16);
        const int p = pt * 16 + lm;
        *reinterpret_cast<uint2*>(Hs + p * 256 + (((nt * 16 + lh * 4) * 2) ^ xorm)) = wv;
      }
    }
  }

  // ================= final layer : [128 -> 2] via MFMA =================
  {
    const float bl0 = bL[0], bl1 = bL[1];
#pragma unroll
    for (int pt2 = 0; pt2 < 2; ++pt2) {
      f32x4 accL = {0.f, 0.f, 0.f, 0.f};
      const int p = pt2 * 16 + lm;
#pragma unroll
      for (int ks = 0; ks < 4; ++ks) {
        const bf16x8 bfr = __builtin_bit_cast(bf16x8,
            *reinterpret_cast<const uint4*>(Hs + p * 256 + ((ks * 64 + lh * 16) ^ xorm)));
        const bf16x8 a = __builtin_bit_cast(bf16x8,
            *reinterpret_cast<const uint4*>(wsb + WS_WLT_B + ks * 1024 + lane * 16));
        accL = __builtin_amdgcn_mfma_f32_16x16x32_bf16(a, bfr, accL, 0, 0, 0);
      }
      if (lh == 0) {
        float2 o;
        o.x = accL[0] + bl0;
        o.y = accL[1] + bl1;
        *reinterpret_cast<float2*>(out + (size_t)(row0 + p) * 2) = o;
      }
    }
  }
}

extern "C" void kernel_launch(void* const* d_in, const int* in_sizes, int n_in,
                              void* d_out, int out_size, void* d_ws, size_t ws_size,
                              hipStream_t stream) {
  const float* X     = (const float*)d_in[0];
  const float* numin = (const float*)d_in[1];
  const float* numax = (const float*)d_in[2];
  const float* W0    = (const float*)d_in[3];
  const float* b0    = (const float*)d_in[4];
  const float* Wh    = (const float*)d_in[5];
  const float* bh    = (const float*)d_in[6];
  const float* WL    = (const float*)d_in[7];
  const float* bL    = (const float*)d_in[8];
  unsigned short* ws = (unsigned short*)d_ws;
  float* out = (float*)d_out;

  hipLaunchKernelGGL(prep_kernel, dim3(344), dim3(256), 0, stream, W0, Wh, WL, ws);
  hipLaunchKernelGGL(mlp_kernel, dim3(8192), dim3(64), 0, stream,
                     X, numin, numax, b0, bh, bL, ws, out);
}